// Round 1
// baseline (503.429 us; speedup 1.0000x reference)
//
#include <hip/hip_runtime.h>
#include <hip/hip_bf16.h>
#include <stdint.h>

#define D_MODEL 1024
#define D_FF    2048
#define HEADS   16
#define DK      64
#define SEQ     2048
#define BATCH   2
#define ROWS    (BATCH * SEQ)   // 4096

typedef __bf16 bf16x8 __attribute__((ext_vector_type(8)));
typedef float  f32x4  __attribute__((ext_vector_type(4)));

__device__ inline unsigned short f2bf(float f) {
    union { float f; uint32_t u; } c; c.f = f;
    uint32_t r = c.u + 0x7fff + ((c.u >> 16) & 1);
    return (unsigned short)(r >> 16);
}

__device__ inline void gload_lds16(const void* g, void* l) {
    __builtin_amdgcn_global_load_lds(
        (const __attribute__((address_space(1))) uint32_t*)g,
        (__attribute__((address_space(3))) uint32_t*)l, 16, 0, 0);
}

// ---------------- weight conversion (fp32 -> bf16 bits) ----------------
__global__ __launch_bounds__(256)
void cvt_weights(const float* __restrict__ s0, const float* __restrict__ s1,
                 const float* __restrict__ s2, const float* __restrict__ s3,
                 const float* __restrict__ s4, const float* __restrict__ s5,
                 unsigned short* __restrict__ dst) {
    size_t i = ((size_t)blockIdx.x * 256 + threadIdx.x) * 4;
    const float* src; size_t off;
    const size_t M1 = 1048576;
    if      (i < 1*M1) { src = s0; off = i; }
    else if (i < 2*M1) { src = s1; off = i - 1*M1; }
    else if (i < 3*M1) { src = s2; off = i - 2*M1; }
    else if (i < 4*M1) { src = s3; off = i - 3*M1; }
    else if (i < 6*M1) { src = s4; off = i - 4*M1; }
    else               { src = s5; off = i - 6*M1; }
    float4 v = *(const float4*)(src + off);
    ushort4 o;
    o.x = f2bf(v.x); o.y = f2bf(v.y); o.z = f2bf(v.z); o.w = f2bf(v.w);
    *(ushort4*)(dst + i) = o;
}

// ---------------- layernorm (fp32 in -> bf16 out) ----------------
__global__ __launch_bounds__(256)
void ln_bf16(const float* __restrict__ x, const float* __restrict__ g,
             const float* __restrict__ b, unsigned short* __restrict__ out) {
    const int row = blockIdx.x;
    const int tid = threadIdx.x;
    const float4 v = ((const float4*)(x + (size_t)row * D_MODEL))[tid];
    float s = v.x + v.y + v.z + v.w;
    float q = v.x * v.x + v.y * v.y + v.z * v.z + v.w * v.w;
    #pragma unroll
    for (int m = 32; m; m >>= 1) { s += __shfl_xor(s, m); q += __shfl_xor(q, m); }
    __shared__ float ss[4], sq[4];
    const int wave = tid >> 6, lane = tid & 63;
    if (lane == 0) { ss[wave] = s; sq[wave] = q; }
    __syncthreads();
    s = ss[0] + ss[1] + ss[2] + ss[3];
    q = sq[0] + sq[1] + sq[2] + sq[3];
    const float mean = s * (1.f / D_MODEL);
    const float var  = q * (1.f / D_MODEL) - mean * mean;
    const float rstd = rsqrtf(var + 1e-5f);
    const float4 gv = ((const float4*)g)[tid];
    const float4 bv = ((const float4*)b)[tid];
    ushort4 o;
    o.x = f2bf((v.x - mean) * rstd * gv.x + bv.x);
    o.y = f2bf((v.y - mean) * rstd * gv.y + bv.y);
    o.z = f2bf((v.z - mean) * rstd * gv.z + bv.z);
    o.w = f2bf((v.w - mean) * rstd * gv.w + bv.w);
    *(ushort4*)(out + (size_t)row * D_MODEL + tid * 4) = o;
}

// ---------------- GEMM: C[M,N] = A[M,K] @ B[N,K]^T (+bias, epilogues) ----
// MODE 0: bf16 out = acc + bias
// MODE 1: bf16 out = relu(acc + bias)
// MODE 2: f32  out = acc + bias + res
template<int MODE>
__global__ __launch_bounds__(256)
void gemm_bt(const unsigned short* __restrict__ A, const unsigned short* __restrict__ B,
             const float* __restrict__ bias, const float* __restrict__ res,
             unsigned short* __restrict__ outB, float* __restrict__ outF,
             int M, int N, int K) {
    __shared__ unsigned short As[128 * 32];
    __shared__ unsigned short Bs[128 * 32];
    const int tid  = threadIdx.x;
    const int wave = tid >> 6, lane = tid & 63;
    const int row0 = blockIdx.y * 128, col0 = blockIdx.x * 128;
    const int wr = (wave >> 1) * 64, wc = (wave & 1) * 64;
    const int lrow = lane & 15;
    const int lk   = (lane >> 4) * 8;

    f32x4 acc[4][4] = {};

    for (int kt = 0; kt < K; kt += 32) {
        #pragma unroll
        for (int it = 0; it < 2; ++it) {
            const int e = it * 2048 + wave * 512 + lane * 8;
            const int r = e >> 5, c = e & 31;
            gload_lds16(A + (size_t)(row0 + r) * K + kt + c, &As[it * 2048 + wave * 512]);
            gload_lds16(B + (size_t)(col0 + r) * K + kt + c, &Bs[it * 2048 + wave * 512]);
        }
        __syncthreads();
        bf16x8 a[4], b[4];
        #pragma unroll
        for (int i = 0; i < 4; ++i)
            a[i] = *(const bf16x8*)&As[(wr + i * 16 + lrow) * 32 + lk];
        #pragma unroll
        for (int j = 0; j < 4; ++j)
            b[j] = *(const bf16x8*)&Bs[(wc + j * 16 + lrow) * 32 + lk];
        #pragma unroll
        for (int i = 0; i < 4; ++i)
            #pragma unroll
            for (int j = 0; j < 4; ++j)
                acc[i][j] = __builtin_amdgcn_mfma_f32_16x16x32_bf16(a[i], b[j], acc[i][j], 0, 0, 0);
        __syncthreads();
    }

    #pragma unroll
    for (int i = 0; i < 4; ++i) {
        #pragma unroll
        for (int j = 0; j < 4; ++j) {
            const int col = col0 + wc + j * 16 + (lane & 15);
            const float bvv = bias[col];
            #pragma unroll
            for (int r = 0; r < 4; ++r) {
                const int row = row0 + wr + i * 16 + (lane >> 4) * 4 + r;
                float v = acc[i][j][r] + bvv;
                if (MODE == 0) {
                    outB[(size_t)row * N + col] = f2bf(v);
                } else if (MODE == 1) {
                    outB[(size_t)row * N + col] = f2bf(fmaxf(v, 0.f));
                } else {
                    outF[(size_t)row * N + col] = v + res[(size_t)row * N + col];
                }
            }
        }
    }
}

// ---------------- flash attention ----------------
// Q,K,V: bf16 [ROWS, D_MODEL] with head h at cols h*64..h*64+63. O same layout.
__global__ __launch_bounds__(256)
void attn_kernel(const unsigned short* __restrict__ Qg, const unsigned short* __restrict__ Kg,
                 const unsigned short* __restrict__ Vg, unsigned short* __restrict__ Og) {
    __shared__ unsigned short Ks[64 * 64];
    __shared__ unsigned short Vt[64 * 64];   // transposed: Vt[d][key]
    __shared__ unsigned short Ps[64 * 64];   // per-wave 16-row slabs
    const int tid = threadIdx.x, wave = tid >> 6, lane = tid & 63;
    const int qt = blockIdx.x;         // 0..31 q tiles of 64
    const int bh = blockIdx.y;         // 0..31
    const int b = bh >> 4, h = bh & 15;
    const size_t rowbase = (size_t)b * SEQ;
    const int colh = h * DK;

    // Q fragments (held in registers for the whole kernel)
    bf16x8 aQ[2];
    {
        const int qrow = qt * 64 + wave * 16 + (lane & 15);
        const unsigned short* qp = Qg + (rowbase + qrow) * D_MODEL + colh + (lane >> 4) * 8;
        aQ[0] = *(const bf16x8*)qp;
        aQ[1] = *(const bf16x8*)(qp + 32);
    }

    f32x4 oacc[4] = {};
    float mrun[4], lrun[4];
    #pragma unroll
    for (int r = 0; r < 4; ++r) { mrun[r] = -1e30f; lrun[r] = 0.f; }

    for (int kv0 = 0; kv0 < SEQ; kv0 += 64) {
        // stage K tile [64 keys x 64 d]
        #pragma unroll
        for (int it = 0; it < 2; ++it) {
            const int e = it * 2048 + wave * 512 + lane * 8;
            const int r = e >> 6, c = e & 63;
            gload_lds16(Kg + (rowbase + kv0 + r) * D_MODEL + colh + c, &Ks[it * 2048 + wave * 512]);
        }
        // stage V transposed
        #pragma unroll
        for (int it = 0; it < 2; ++it) {
            const int e = it * 2048 + tid * 8;
            const int r = e >> 6, c = e & 63;
            const unsigned short* vp = Vg + (rowbase + kv0 + r) * D_MODEL + colh + c;
            ushort4 v0 = *(const ushort4*)vp;
            ushort4 v1 = *(const ushort4*)(vp + 4);
            Vt[(c + 0) * 64 + r] = v0.x; Vt[(c + 1) * 64 + r] = v0.y;
            Vt[(c + 2) * 64 + r] = v0.z; Vt[(c + 3) * 64 + r] = v0.w;
            Vt[(c + 4) * 64 + r] = v1.x; Vt[(c + 5) * 64 + r] = v1.y;
            Vt[(c + 6) * 64 + r] = v1.z; Vt[(c + 7) * 64 + r] = v1.w;
        }
        __syncthreads();

        // S = Q @ K^T for this wave's 16 q-rows x 64 keys
        f32x4 sfr[4];
        #pragma unroll
        for (int j = 0; j < 4; ++j) {
            bf16x8 b0 = *(const bf16x8*)&Ks[(j * 16 + (lane & 15)) * 64 + (lane >> 4) * 8];
            bf16x8 b1 = *(const bf16x8*)&Ks[(j * 16 + (lane & 15)) * 64 + 32 + (lane >> 4) * 8];
            f32x4 z = {0.f, 0.f, 0.f, 0.f};
            z = __builtin_amdgcn_mfma_f32_16x16x32_bf16(aQ[0], b0, z, 0, 0, 0);
            z = __builtin_amdgcn_mfma_f32_16x16x32_bf16(aQ[1], b1, z, 0, 0, 0);
            #pragma unroll
            for (int r = 0; r < 4; ++r) z[r] *= 0.125f;   // 1/sqrt(dk)
            sfr[j] = z;
        }

        // online softmax
        float mx[4];
        #pragma unroll
        for (int r = 0; r < 4; ++r) {
            float t = fmaxf(fmaxf(sfr[0][r], sfr[1][r]), fmaxf(sfr[2][r], sfr[3][r]));
            #pragma unroll
            for (int msk = 1; msk < 16; msk <<= 1) t = fmaxf(t, __shfl_xor(t, msk));
            mx[r] = t;
        }
        float corr[4], rsum[4];
        #pragma unroll
        for (int r = 0; r < 4; ++r) {
            const float mn = fmaxf(mrun[r], mx[r]);
            corr[r] = __expf(mrun[r] - mn);
            mrun[r] = mn;
            rsum[r] = 0.f;
        }
        #pragma unroll
        for (int j = 0; j < 4; ++j) {
            #pragma unroll
            for (int r = 0; r < 4; ++r) {
                const float p = __expf(sfr[j][r] - mrun[r]);
                rsum[r] += p;
                Ps[(wave * 16 + (lane >> 4) * 4 + r) * 64 + j * 16 + (lane & 15)] = f2bf(p);
            }
        }
        #pragma unroll
        for (int r = 0; r < 4; ++r) {
            #pragma unroll
            for (int msk = 1; msk < 16; msk <<= 1) rsum[r] += __shfl_xor(rsum[r], msk);
            lrun[r] = lrun[r] * corr[r] + rsum[r];
        }
        #pragma unroll
        for (int j = 0; j < 4; ++j)
            #pragma unroll
            for (int r = 0; r < 4; ++r) oacc[j][r] *= corr[r];

        // O += P @ V   (P from this wave's LDS slab, V transposed in LDS)
        #pragma unroll
        for (int kk = 0; kk < 2; ++kk) {
            bf16x8 ap = *(const bf16x8*)&Ps[(wave * 16 + (lane & 15)) * 64 + kk * 32 + (lane >> 4) * 8];
            #pragma unroll
            for (int j = 0; j < 4; ++j) {
                bf16x8 bv = *(const bf16x8*)&Vt[(j * 16 + (lane & 15)) * 64 + kk * 32 + (lane >> 4) * 8];
                oacc[j] = __builtin_amdgcn_mfma_f32_16x16x32_bf16(ap, bv, oacc[j], 0, 0, 0);
            }
        }
        __syncthreads();
    }

    // epilogue: divide by l, write bf16
    #pragma unroll
    for (int j = 0; j < 4; ++j) {
        #pragma unroll
        for (int r = 0; r < 4; ++r) {
            const int qrow = qt * 64 + wave * 16 + (lane >> 4) * 4 + r;
            const int d = j * 16 + (lane & 15);
            Og[(rowbase + qrow) * D_MODEL + colh + d] = f2bf(oacc[j][r] / lrun[r]);
        }
    }
}

// ---------------- launch ----------------
extern "C" void kernel_launch(void* const* d_in, const int* in_sizes, int n_in,
                              void* d_out, int out_size, void* d_ws, size_t ws_size,
                              hipStream_t stream) {
    const float* x    = (const float*)d_in[0];
    const float* ln1g = (const float*)d_in[1];
    const float* ln1b = (const float*)d_in[2];
    const float* wq   = (const float*)d_in[3];
    const float* bq   = (const float*)d_in[4];
    const float* wk   = (const float*)d_in[5];
    const float* bk   = (const float*)d_in[6];
    const float* wv   = (const float*)d_in[7];
    const float* bv   = (const float*)d_in[8];
    const float* wo   = (const float*)d_in[9];
    const float* bo   = (const float*)d_in[10];
    const float* ln2g = (const float*)d_in[11];
    const float* ln2b = (const float*)d_in[12];
    const float* w1   = (const float*)d_in[13];
    const float* b1   = (const float*)d_in[14];
    const float* w2   = (const float*)d_in[15];
    const float* b2   = (const float*)d_in[16];

    unsigned short* wqb = (unsigned short*)d_ws;          // 1M elems each
    unsigned short* wkb = wqb + (1u << 20);
    unsigned short* wvb = wkb + (1u << 20);
    unsigned short* wob = wvb + (1u << 20);
    unsigned short* w1b = wob + (1u << 20);               // 2M
    unsigned short* w2b = w1b + (1u << 21);               // 2M
    unsigned short* x2  = w2b + (1u << 21);               // 4096*1024
    unsigned short* qb  = x2 + (size_t)ROWS * D_MODEL;
    unsigned short* kb  = qb + (size_t)ROWS * D_MODEL;
    unsigned short* vb  = kb + (size_t)ROWS * D_MODEL;
    float*          x1  = (float*)(vb + (size_t)ROWS * D_MODEL);
    unsigned short* attn_o = x2;   // reuse (x2 dead after QKV GEMMs)
    unsigned short* x4  = qb;      // reuse (q dead after attention)
    unsigned short* hb  = kb;      // reuse (k,v dead after attention; spans kb+vb)

    cvt_weights<<<8192, 256, 0, stream>>>(wq, wk, wv, wo, w1, w2, wqb);
    ln_bf16<<<ROWS, 256, 0, stream>>>(x, ln1g, ln1b, x2);

    dim3 g1(D_MODEL / 128, ROWS / 128);   // (8, 32)
    gemm_bt<0><<<g1, 256, 0, stream>>>(x2, wqb, bq, nullptr, qb, nullptr, ROWS, D_MODEL, D_MODEL);
    gemm_bt<0><<<g1, 256, 0, stream>>>(x2, wkb, bk, nullptr, kb, nullptr, ROWS, D_MODEL, D_MODEL);
    gemm_bt<0><<<g1, 256, 0, stream>>>(x2, wvb, bv, nullptr, vb, nullptr, ROWS, D_MODEL, D_MODEL);

    attn_kernel<<<dim3(SEQ / 64, BATCH * HEADS), 256, 0, stream>>>(qb, kb, vb, attn_o);

    gemm_bt<2><<<g1, 256, 0, stream>>>(attn_o, wob, bo, x, nullptr, x1, ROWS, D_MODEL, D_MODEL);

    ln_bf16<<<ROWS, 256, 0, stream>>>(x1, ln2g, ln2b, x4);

    dim3 g2(D_FF / 128, ROWS / 128);      // (16, 32)
    gemm_bt<1><<<g2, 256, 0, stream>>>(x4, w1b, b1, nullptr, hb, nullptr, ROWS, D_FF, D_MODEL);

    gemm_bt<2><<<g1, 256, 0, stream>>>(hb, w2b, b2, x1, nullptr, (float*)d_out, ROWS, D_MODEL, D_FF);
}

// Round 3
// 362.429 us; speedup vs baseline: 1.3890x; 1.3890x over previous
//
#include <hip/hip_runtime.h>
#include <hip/hip_bf16.h>
#include <stdint.h>

#define D_MODEL 1024
#define D_FF    2048
#define HEADS   16
#define DK      64
#define SEQ     2048
#define BATCH   2
#define ROWS    (BATCH * SEQ)   // 4096

typedef __bf16 bf16x8 __attribute__((ext_vector_type(8)));
typedef unsigned short u16x8 __attribute__((ext_vector_type(8)));
typedef float  f32x4  __attribute__((ext_vector_type(4)));

__device__ inline unsigned short f2bf(float f) {
    union { float f; uint32_t u; } c; c.f = f;
    uint32_t r = c.u + 0x7fff + ((c.u >> 16) & 1);
    return (unsigned short)(r >> 16);
}

__device__ inline void gload_lds16(const void* g, void* l) {
    __builtin_amdgcn_global_load_lds(
        (const __attribute__((address_space(1))) uint32_t*)g,
        (__attribute__((address_space(3))) uint32_t*)l, 16, 0, 0);
}

// ---------------- weight conversion (fp32 -> bf16 bits) ----------------
__global__ __launch_bounds__(256)
void cvt_weights(const float* __restrict__ s0, const float* __restrict__ s1,
                 const float* __restrict__ s2, const float* __restrict__ s3,
                 const float* __restrict__ s4, const float* __restrict__ s5,
                 unsigned short* __restrict__ dst) {
    size_t i = ((size_t)blockIdx.x * 256 + threadIdx.x) * 4;
    const float* src; size_t off;
    const size_t M1 = 1048576;
    if      (i < 1*M1) { src = s0; off = i; }
    else if (i < 2*M1) { src = s1; off = i - 1*M1; }
    else if (i < 3*M1) { src = s2; off = i - 2*M1; }
    else if (i < 4*M1) { src = s3; off = i - 3*M1; }
    else if (i < 6*M1) { src = s4; off = i - 4*M1; }
    else               { src = s5; off = i - 6*M1; }
    float4 v = *(const float4*)(src + off);
    ushort4 o;
    o.x = f2bf(v.x); o.y = f2bf(v.y); o.z = f2bf(v.z); o.w = f2bf(v.w);
    *(ushort4*)(dst + i) = o;
}

__global__ __launch_bounds__(256)
void cvt_bias(const float* __restrict__ bq, const float* __restrict__ bk,
              const float* __restrict__ bv, float* __restrict__ dst) {
    int i = blockIdx.x * 256 + threadIdx.x;   // 3072 total
    const float* s = (i < 1024) ? bq : ((i < 2048) ? bk : bv);
    dst[i] = s[i & 1023];
}

// ---------------- layernorm (fp32 in -> bf16 out) ----------------
__global__ __launch_bounds__(256)
void ln_bf16(const float* __restrict__ x, const float* __restrict__ g,
             const float* __restrict__ b, unsigned short* __restrict__ out) {
    const int row = blockIdx.x;
    const int tid = threadIdx.x;
    const float4 v = ((const float4*)(x + (size_t)row * D_MODEL))[tid];
    float s = v.x + v.y + v.z + v.w;
    float q = v.x * v.x + v.y * v.y + v.z * v.z + v.w * v.w;
    #pragma unroll
    for (int m = 32; m; m >>= 1) { s += __shfl_xor(s, m); q += __shfl_xor(q, m); }
    __shared__ float ss[4], sq[4];
    const int wave = tid >> 6, lane = tid & 63;
    if (lane == 0) { ss[wave] = s; sq[wave] = q; }
    __syncthreads();
    s = ss[0] + ss[1] + ss[2] + ss[3];
    q = sq[0] + sq[1] + sq[2] + sq[3];
    const float mean = s * (1.f / D_MODEL);
    const float var  = q * (1.f / D_MODEL) - mean * mean;
    const float rstd = rsqrtf(var + 1e-5f);
    const float4 gv = ((const float4*)g)[tid];
    const float4 bv = ((const float4*)b)[tid];
    ushort4 o;
    o.x = f2bf((v.x - mean) * rstd * gv.x + bv.x);
    o.y = f2bf((v.y - mean) * rstd * gv.y + bv.y);
    o.z = f2bf((v.z - mean) * rstd * gv.z + bv.z);
    o.w = f2bf((v.w - mean) * rstd * gv.w + bv.w);
    *(ushort4*)(out + (size_t)row * D_MODEL + tid * 4) = o;
}

// ---------------- GEMM: C[M,N] = A[M,K] @ B[N,K]^T (+bias, epilogues) ----
// MODE 0: bf16 out = acc + bias
// MODE 1: bf16 out = relu(acc + bias)
// MODE 2: f32  out = acc + bias + res
template<int BM, int BN, int MODE>
__global__ __launch_bounds__(256)
void gemm_bt(const unsigned short* __restrict__ A, const unsigned short* __restrict__ B,
             const float* __restrict__ bias, const float* __restrict__ res,
             unsigned short* __restrict__ outB, float* __restrict__ outF,
             int M, int N, int K) {
    __shared__ unsigned short As[BM * 32];
    __shared__ unsigned short Bs[BN * 32];
    const int tid  = threadIdx.x;
    const int wave = tid >> 6, lane = tid & 63;
    const int row0 = blockIdx.y * BM, col0 = blockIdx.x * BN;
    const int wr = (wave >> 1) * (BM / 2), wc = (wave & 1) * (BN / 2);
    const int lrow = lane & 15;
    const int lk   = (lane >> 4) * 8;
    constexpr int MI = BM / 32, NJ = BN / 32;

    f32x4 acc[MI][NJ] = {};

    for (int kt = 0; kt < K; kt += 32) {
        #pragma unroll
        for (int it = 0; it < BM / 64; ++it) {
            const int e = it * 2048 + wave * 512 + lane * 8;
            gload_lds16(A + (size_t)(row0 + (e >> 5)) * K + kt + (e & 31),
                        &As[it * 2048 + wave * 512]);
        }
        #pragma unroll
        for (int it = 0; it < BN / 64; ++it) {
            const int e = it * 2048 + wave * 512 + lane * 8;
            gload_lds16(B + (size_t)(col0 + (e >> 5)) * K + kt + (e & 31),
                        &Bs[it * 2048 + wave * 512]);
        }
        __syncthreads();
        bf16x8 a[MI], b[NJ];
        #pragma unroll
        for (int i = 0; i < MI; ++i)
            a[i] = *(const bf16x8*)&As[(wr + i * 16 + lrow) * 32 + lk];
        #pragma unroll
        for (int j = 0; j < NJ; ++j)
            b[j] = *(const bf16x8*)&Bs[(wc + j * 16 + lrow) * 32 + lk];
        #pragma unroll
        for (int i = 0; i < MI; ++i)
            #pragma unroll
            for (int j = 0; j < NJ; ++j)
                acc[i][j] = __builtin_amdgcn_mfma_f32_16x16x32_bf16(a[i], b[j], acc[i][j], 0, 0, 0);
        __syncthreads();
    }

    #pragma unroll
    for (int i = 0; i < MI; ++i) {
        #pragma unroll
        for (int j = 0; j < NJ; ++j) {
            const int col = col0 + wc + j * 16 + (lane & 15);
            const float bvv = bias[col];
            #pragma unroll
            for (int r = 0; r < 4; ++r) {
                const int row = row0 + wr + i * 16 + (lane >> 4) * 4 + r;
                float v = acc[i][j][r] + bvv;
                if (MODE == 0) {
                    outB[(size_t)row * N + col] = f2bf(v);
                } else if (MODE == 1) {
                    outB[(size_t)row * N + col] = f2bf(fmaxf(v, 0.f));
                } else {
                    outF[(size_t)row * N + col] = v + res[(size_t)row * N + col];
                }
            }
        }
    }
}

// ---------------- flash attention (swapped QK^T; no tr_read) ----------------
// Q,K,V at row stride ldq (head h at cols h*64..h*64+63). O: [ROWS][D_MODEL].
// LDS layouts (all phase-conflict-free, see analysis):
//   Ks[key][64d] rows, 8-elem chunk slot s holds source chunk s^(key&7)
//   Vt[d][72]  : V^T rows (64 keys + pad 8), linear
//   Ps[q][64]  : per-wave P rows, 8-elem chunk slot s holds keys chunk s^(q&7)
__global__ __launch_bounds__(256)
void attn_kernel(const unsigned short* __restrict__ Qg, const unsigned short* __restrict__ Kg,
                 const unsigned short* __restrict__ Vg, unsigned short* __restrict__ Og,
                 int ldq) {
    __shared__ unsigned short Ks[2][4096];
    __shared__ unsigned short Vt[2][64 * 72];
    __shared__ unsigned short Ps[4][1024];
    const int tid = threadIdx.x, wave = tid >> 6, lane = tid & 63;
    const int qt = blockIdx.x, bh = blockIdx.y;
    const int bb = bh >> 4, h = bh & 15;
    const size_t rowbase = (size_t)bb * SEQ;
    const int colh = h * DK;
    const int lq = lane & 15, lg = lane >> 4;

    // Q fragment (B operand): lane holds Q[q=lq][d = half*32 + lg*8 + e]
    bf16x8 aQ[2];
    {
        const int qrow = qt * 64 + wave * 16 + lq;
        const unsigned short* qp = Qg + (rowbase + qrow) * (size_t)ldq + colh + lg * 8;
        aQ[0] = *(const bf16x8*)qp;
        aQ[1] = *(const bf16x8*)(qp + 32);
    }

    f32x4 oacc[4] = {};
    float mrun = -1e30f, lrun = 0.f;
    u16x8 vreg0, vreg1;

    auto stageK = [&](int bf, int kv0) {
        #pragma unroll
        for (int it = 0; it < 2; ++it) {
            const int c = it * 256 + wave * 64 + lane;
            const int kr = c >> 3, cc = (c & 7) ^ (kr & 7);
            gload_lds16(Kg + (rowbase + kv0 + kr) * (size_t)ldq + colh + cc * 8,
                        &Ks[bf][it * 2048 + wave * 512]);
        }
    };
    auto loadV = [&](int kv0) {
        const unsigned short* vp = Vg + (rowbase + kv0 + lane) * (size_t)ldq + colh + wave * 16;
        vreg0 = *(const u16x8*)vp;
        vreg1 = *(const u16x8*)(vp + 8);
    };
    auto writeV = [&](int bf) {
        #pragma unroll
        for (int e = 0; e < 8; ++e) {
            Vt[bf][(wave * 16 + e) * 72 + lane]     = vreg0[e];
            Vt[bf][(wave * 16 + 8 + e) * 72 + lane] = vreg1[e];
        }
    };

    stageK(0, 0);
    loadV(0);
    writeV(0);

    for (int t = 0; t < SEQ / 64; ++t) {
        __syncthreads();                         // tile t staged (K gloads + V writes drained)
        if (t + 1 < SEQ / 64) { stageK((t + 1) & 1, (t + 1) * 64); loadV((t + 1) * 64); }
        const int bf = t & 1;

        // S^T = K @ Q^T : lane holds S[q=lq][key = j*16 + lg*4 + r] (scaled)
        f32x4 sfr[4];
        #pragma unroll
        for (int j = 0; j < 4; ++j) {
            const int key = j * 16 + lq;
            bf16x8 k0 = *(const bf16x8*)&Ks[bf][key * 64 + ((lg * 8) ^ ((lq & 7) * 8))];
            bf16x8 k1 = *(const bf16x8*)&Ks[bf][key * 64 + ((32 + lg * 8) ^ ((lq & 7) * 8))];
            f32x4 z = {0.f, 0.f, 0.f, 0.f};
            z = __builtin_amdgcn_mfma_f32_16x16x32_bf16(k0, aQ[0], z, 0, 0, 0);
            z = __builtin_amdgcn_mfma_f32_16x16x32_bf16(k1, aQ[1], z, 0, 0, 0);
            sfr[j] = z * 0.125f;
        }

        // online softmax for q=lq (16 local vals; lane groups hold disjoint keys)
        float mx = -1e30f;
        #pragma unroll
        for (int j = 0; j < 4; ++j)
            #pragma unroll
            for (int r = 0; r < 4; ++r) mx = fmaxf(mx, sfr[j][r]);
        mx = fmaxf(mx, __shfl_xor(mx, 16));
        mx = fmaxf(mx, __shfl_xor(mx, 32));
        const float mn = fmaxf(mrun, mx);
        const float corr = __expf(mrun - mn);
        mrun = mn;
        float rsum = 0.f;
        #pragma unroll
        for (int j = 0; j < 4; ++j) {
            ushort4 pw;
            float p0 = __expf(sfr[j][0] - mn), p1 = __expf(sfr[j][1] - mn);
            float p2 = __expf(sfr[j][2] - mn), p3 = __expf(sfr[j][3] - mn);
            rsum += (p0 + p1) + (p2 + p3);
            pw.x = f2bf(p0); pw.y = f2bf(p1); pw.z = f2bf(p2); pw.w = f2bf(p3);
            // keys j*16+lg*4+{0..3} -> row lq, chunk 2j+(lg>>1), slot-XOR, half lg&1
            *(ushort4*)&Ps[wave][lq * 64 + (((2 * j + (lg >> 1)) ^ (lq & 7)) * 8) + (lg & 1) * 4] = pw;
        }
        rsum += __shfl_xor(rsum, 16);
        rsum += __shfl_xor(rsum, 32);
        lrun = lrun * corr + rsum;

        // rescale O (corr for q=lg*4+r fetched from lane owning that q)
        float corr4[4];
        #pragma unroll
        for (int r = 0; r < 4; ++r) corr4[r] = __shfl(corr, lg * 4 + r, 16);
        #pragma unroll
        for (int j = 0; j < 4; ++j)
            #pragma unroll
            for (int r = 0; r < 4; ++r) oacc[j][r] *= corr4[r];

        // O += P @ V  (A: P[q=lq][keys kk*32+lg*8+e]; B: V^T[d=j*16+lq][same keys])
        #pragma unroll
        for (int kk = 0; kk < 2; ++kk) {
            bf16x8 ap = *(const bf16x8*)&Ps[wave][lq * 64 + (((kk * 4 + lg) ^ (lq & 7)) * 8)];
            #pragma unroll
            for (int j = 0; j < 4; ++j) {
                bf16x8 bv = *(const bf16x8*)&Vt[bf][(j * 16 + lq) * 72 + kk * 32 + lg * 8];
                oacc[j] = __builtin_amdgcn_mfma_f32_16x16x32_bf16(ap, bv, oacc[j], 0, 0, 0);
            }
        }

        if (t + 1 < SEQ / 64) writeV((t + 1) & 1);   // buf^1 readers finished before top barrier
    }

    // epilogue: O[q = lg*4+r][d = j*16+lq] / l[q]
    float linv[4];
    #pragma unroll
    for (int r = 0; r < 4; ++r) linv[r] = 1.f / __shfl(lrun, lg * 4 + r, 16);
    #pragma unroll
    for (int j = 0; j < 4; ++j) {
        #pragma unroll
        for (int r = 0; r < 4; ++r) {
            const int qrow = qt * 64 + wave * 16 + lg * 4 + r;
            Og[(rowbase + qrow) * D_MODEL + colh + j * 16 + lq] = f2bf(oacc[j][r] * linv[r]);
        }
    }
}

// ---------------- launch ----------------
extern "C" void kernel_launch(void* const* d_in, const int* in_sizes, int n_in,
                              void* d_out, int out_size, void* d_ws, size_t ws_size,
                              hipStream_t stream) {
    const float* x    = (const float*)d_in[0];
    const float* ln1g = (const float*)d_in[1];
    const float* ln1b = (const float*)d_in[2];
    const float* wq   = (const float*)d_in[3];
    const float* bq   = (const float*)d_in[4];
    const float* wk   = (const float*)d_in[5];
    const float* bk   = (const float*)d_in[6];
    const float* wv   = (const float*)d_in[7];
    const float* bv   = (const float*)d_in[8];
    const float* wo   = (const float*)d_in[9];
    const float* bo   = (const float*)d_in[10];
    const float* ln2g = (const float*)d_in[11];
    const float* ln2b = (const float*)d_in[12];
    const float* w1   = (const float*)d_in[13];
    const float* b1   = (const float*)d_in[14];
    const float* w2   = (const float*)d_in[15];
    const float* b2   = (const float*)d_in[16];

    const size_t M1 = 1048576;
    unsigned short* wqkvb = (unsigned short*)d_ws;        // [3072][1024] bf16
    unsigned short* wob   = wqkvb + 3 * M1;
    unsigned short* w1b   = wqkvb + 4 * M1;
    unsigned short* w2b   = wqkvb + 6 * M1;
    float*          bias3 = (float*)(wqkvb + 8 * M1);     // 3072 f32
    unsigned short* x2    = (unsigned short*)(bias3 + 3072);
    unsigned short* qkv   = x2 + (size_t)ROWS * D_MODEL;  // [4096][3072] bf16
    float*          x1    = (float*)(qkv + (size_t)ROWS * 3072);
    unsigned short* attn_o = x2;                          // reuse
    unsigned short* x4    = qkv;                          // reuse
    unsigned short* hb    = qkv + (size_t)ROWS * D_MODEL; // reuse, [4096][2048]

    cvt_weights<<<8192, 256, 0, stream>>>(wq, wk, wv, wo, w1, w2, wqkvb);
    cvt_bias<<<12, 256, 0, stream>>>(bq, bk, bv, bias3);
    ln_bf16<<<ROWS, 256, 0, stream>>>(x, ln1g, ln1b, x2);

    // fused QKV: [4096,1024] @ [3072,1024]^T
    gemm_bt<128, 128, 0><<<dim3(24, 32), 256, 0, stream>>>(
        x2, wqkvb, bias3, nullptr, qkv, nullptr, ROWS, 3072, 1024);

    attn_kernel<<<dim3(SEQ / 64, BATCH * HEADS), 256, 0, stream>>>(
        qkv, qkv + 1024, qkv + 2048, attn_o, 3072);

    gemm_bt<128, 64, 2><<<dim3(16, 32), 256, 0, stream>>>(
        attn_o, wob, bo, x, nullptr, x1, ROWS, 1024, 1024);

    ln_bf16<<<ROWS, 256, 0, stream>>>(x1, ln2g, ln2b, x4);

    gemm_bt<128, 128, 1><<<dim3(16, 32), 256, 0, stream>>>(
        x4, w1b, b1, nullptr, hb, nullptr, ROWS, D_FF, 1024);

    gemm_bt<128, 64, 2><<<dim3(16, 32), 256, 0, stream>>>(
        hb, w2b, b2, x1, nullptr, (float*)d_out, ROWS, 1024, D_FF);
}

// Round 6
// 330.275 us; speedup vs baseline: 1.5243x; 1.0974x over previous
//
#include <hip/hip_runtime.h>
#include <hip/hip_bf16.h>
#include <stdint.h>

#define D_MODEL 1024
#define D_FF    2048
#define HEADS   16
#define DK      64
#define SEQ     2048
#define BATCH   2
#define ROWS    (BATCH * SEQ)   // 4096

typedef __bf16 bf16x8 __attribute__((ext_vector_type(8)));
typedef unsigned short u16x8 __attribute__((ext_vector_type(8)));
typedef float  f32x4  __attribute__((ext_vector_type(4)));
typedef uint32_t u32x4 __attribute__((ext_vector_type(4)));

__device__ inline unsigned short f2bf(float f) {
    union { float f; uint32_t u; } c; c.f = f;
    uint32_t r = c.u + 0x7fff + ((c.u >> 16) & 1);
    return (unsigned short)(r >> 16);
}

__device__ inline uint32_t fbits(float f) {
    union { float f; uint32_t u; } c; c.f = f; return c.u;
}

__device__ inline void gload_lds16(const void* g, void* l) {
    __builtin_amdgcn_global_load_lds(
        (const __attribute__((address_space(1))) uint32_t*)g,
        (__attribute__((address_space(3))) uint32_t*)l, 16, 0, 0);
}

// ---------------- weight + bias conversion (fp32 -> bf16 / pack) ----------
__global__ __launch_bounds__(256)
void cvt_weights(const float* __restrict__ s0, const float* __restrict__ s1,
                 const float* __restrict__ s2, const float* __restrict__ s3,
                 const float* __restrict__ s4, const float* __restrict__ s5,
                 unsigned short* __restrict__ dst,
                 const float* __restrict__ bq, const float* __restrict__ bk,
                 const float* __restrict__ bv, float* __restrict__ bias3) {
    if (blockIdx.x >= 8192) {
        int i = (blockIdx.x - 8192) * 256 + threadIdx.x;   // 3072 total
        const float* s = (i < 1024) ? bq : ((i < 2048) ? bk : bv);
        bias3[i] = s[i & 1023];
        return;
    }
    size_t i = ((size_t)blockIdx.x * 256 + threadIdx.x) * 4;
    const float* src; size_t off;
    const size_t M1 = 1048576;
    if      (i < 1*M1) { src = s0; off = i; }
    else if (i < 2*M1) { src = s1; off = i - 1*M1; }
    else if (i < 3*M1) { src = s2; off = i - 2*M1; }
    else if (i < 4*M1) { src = s3; off = i - 3*M1; }
    else if (i < 6*M1) { src = s4; off = i - 4*M1; }
    else               { src = s5; off = i - 6*M1; }
    float4 v = *(const float4*)(src + off);
    ushort4 o;
    o.x = f2bf(v.x); o.y = f2bf(v.y); o.z = f2bf(v.z); o.w = f2bf(v.w);
    *(ushort4*)(dst + i) = o;
}

// ---------------- layernorm (fp32 in -> bf16 out) ----------------
__global__ __launch_bounds__(256)
void ln_bf16(const float* __restrict__ x, const float* __restrict__ g,
             const float* __restrict__ b, unsigned short* __restrict__ out) {
    const int row = blockIdx.x;
    const int tid = threadIdx.x;
    const float4 v = ((const float4*)(x + (size_t)row * D_MODEL))[tid];
    float s = v.x + v.y + v.z + v.w;
    float q = v.x * v.x + v.y * v.y + v.z * v.z + v.w * v.w;
    #pragma unroll
    for (int m = 32; m; m >>= 1) { s += __shfl_xor(s, m); q += __shfl_xor(q, m); }
    __shared__ float ss[4], sq[4];
    const int wave = tid >> 6, lane = tid & 63;
    if (lane == 0) { ss[wave] = s; sq[wave] = q; }
    __syncthreads();
    s = ss[0] + ss[1] + ss[2] + ss[3];
    q = sq[0] + sq[1] + sq[2] + sq[3];
    const float mean = s * (1.f / D_MODEL);
    const float var  = q * (1.f / D_MODEL) - mean * mean;
    const float rstd = rsqrtf(var + 1e-5f);
    const float4 gv = ((const float4*)g)[tid];
    const float4 bv = ((const float4*)b)[tid];
    ushort4 o;
    o.x = f2bf((v.x - mean) * rstd * gv.x + bv.x);
    o.y = f2bf((v.y - mean) * rstd * gv.y + bv.y);
    o.z = f2bf((v.z - mean) * rstd * gv.z + bv.z);
    o.w = f2bf((v.w - mean) * rstd * gv.w + bv.w);
    *(ushort4*)(out + (size_t)row * D_MODEL + tid * 4) = o;
}

// ---------------- GEMM: C[M,N] = A[M,K] @ B[N,K]^T (+bias, epilogues) ----
// MODE 0: bf16 out = acc + bias
// MODE 1: bf16 out = relu(acc + bias)
// MODE 2: f32  out = acc + bias + res
template<int BM, int BN, int MODE>
__global__ __launch_bounds__(256)
void gemm_bt(const unsigned short* __restrict__ A, const unsigned short* __restrict__ B,
             const float* __restrict__ bias, const float* __restrict__ res,
             unsigned short* __restrict__ outB, float* __restrict__ outF,
             int M, int N, int K) {
    __shared__ unsigned short As[BM * 32];
    __shared__ unsigned short Bs[BN * 32];
    const int tid  = threadIdx.x;
    const int wave = tid >> 6, lane = tid & 63;
    const int row0 = blockIdx.y * BM, col0 = blockIdx.x * BN;
    const int wr = (wave >> 1) * (BM / 2), wc = (wave & 1) * (BN / 2);
    const int lrow = lane & 15;
    const int lk   = (lane >> 4) * 8;
    constexpr int MI = BM / 32, NJ = BN / 32;

    f32x4 acc[MI][NJ] = {};

    for (int kt = 0; kt < K; kt += 32) {
        #pragma unroll
        for (int it = 0; it < BM / 64; ++it) {
            const int e = it * 2048 + wave * 512 + lane * 8;
            gload_lds16(A + (size_t)(row0 + (e >> 5)) * K + kt + (e & 31),
                        &As[it * 2048 + wave * 512]);
        }
        #pragma unroll
        for (int it = 0; it < BN / 64; ++it) {
            const int e = it * 2048 + wave * 512 + lane * 8;
            gload_lds16(B + (size_t)(col0 + (e >> 5)) * K + kt + (e & 31),
                        &Bs[it * 2048 + wave * 512]);
        }
        __syncthreads();
        bf16x8 a[MI], b[NJ];
        #pragma unroll
        for (int i = 0; i < MI; ++i)
            a[i] = *(const bf16x8*)&As[(wr + i * 16 + lrow) * 32 + lk];
        #pragma unroll
        for (int j = 0; j < NJ; ++j)
            b[j] = *(const bf16x8*)&Bs[(wc + j * 16 + lrow) * 32 + lk];
        #pragma unroll
        for (int i = 0; i < MI; ++i)
            #pragma unroll
            for (int j = 0; j < NJ; ++j)
                acc[i][j] = __builtin_amdgcn_mfma_f32_16x16x32_bf16(a[i], b[j], acc[i][j], 0, 0, 0);
        __syncthreads();
    }

    #pragma unroll
    for (int i = 0; i < MI; ++i) {
        #pragma unroll
        for (int j = 0; j < NJ; ++j) {
            const int col = col0 + wc + j * 16 + (lane & 15);
            const float bvv = bias[col];
            #pragma unroll
            for (int r = 0; r < 4; ++r) {
                const int row = row0 + wr + i * 16 + (lane >> 4) * 4 + r;
                float v = acc[i][j][r] + bvv;
                if (MODE == 0) {
                    outB[(size_t)row * N + col] = f2bf(v);
                } else if (MODE == 1) {
                    outB[(size_t)row * N + col] = f2bf(fmaxf(v, 0.f));
                } else {
                    outF[(size_t)row * N + col] = v + res[(size_t)row * N + col];
                }
            }
        }
    }
}

// ---------------- flash attention (register-resident P) ----------------
// Q,K,V at row stride ldq (head h at cols h*64..h*64+63). O: [ROWS][D_MODEL].
// LDS:
//   Ks[key][64d] rows, 8-elem chunk slot s holds source chunk s^(key&7)  (XOR swz)
//   Vt[d][72]  : V^T rows; columns hold PERMUTED keys: key -> col' =
//                (j6>>1)*32 + lg6*8 + (j6&1)*4 + r6  where key = j6*16+lg6*4+r6.
// k-slot convention for PV (consistent between P-A and V^T-B operands):
//   slot (lg, e) of half kk  <->  key (2kk+(e>>2))*16 + lg*4 + (e&3)
// so the P fragment is each lane's OWN sfr registers (no LDS, no shuffles).
__global__ __launch_bounds__(256, 4)
void attn_kernel(const unsigned short* __restrict__ Qg, const unsigned short* __restrict__ Kg,
                 const unsigned short* __restrict__ Vg, unsigned short* __restrict__ Og,
                 int ldq) {
    __shared__ unsigned short Ks[2][4096];
    __shared__ unsigned short Vt[2][64 * 72];
    const int tid = threadIdx.x, wave = tid >> 6, lane = tid & 63;
    const int qt = blockIdx.x, bh = blockIdx.y;
    const int bb = bh >> 4, h = bh & 15;
    const size_t rowbase = (size_t)bb * SEQ;
    const int colh = h * DK;
    const int lq = lane & 15, lg = lane >> 4;
    const float CEXP = 0.125f * 1.44269504f;   // 1/sqrt(dk) * log2(e)

    // Q fragment (B operand of QK^T): lane holds Q[q=lq][d = half*32 + lg*8 + e]
    bf16x8 aQ[2];
    {
        const int qrow = qt * 64 + wave * 16 + lq;
        const unsigned short* qp = Qg + (rowbase + qrow) * (size_t)ldq + colh + lg * 8;
        aQ[0] = *(const bf16x8*)qp;
        aQ[1] = *(const bf16x8*)(qp + 32);
    }

    f32x4 oacc[4] = {};
    float mrun = -1e30f, lrun = 0.f;
    u16x8 vreg0, vreg1;

    auto stageK = [&](int bf, int kv0) {
        #pragma unroll
        for (int it = 0; it < 2; ++it) {
            const int c = it * 256 + wave * 64 + lane;
            const int kr = c >> 3, cc = (c & 7) ^ (kr & 7);
            gload_lds16(Kg + (rowbase + kv0 + kr) * (size_t)ldq + colh + cc * 8,
                        &Ks[bf][it * 2048 + wave * 512]);
        }
    };
    auto loadV = [&](int kv0) {
        const unsigned short* vp = Vg + (rowbase + kv0 + lane) * (size_t)ldq + colh + wave * 16;
        vreg0 = *(const u16x8*)vp;
        vreg1 = *(const u16x8*)(vp + 8);
    };
    // permuted column for this lane's key (= lane index within tile)
    const int colp = ((lane >> 5) << 5) | (((lane >> 2) & 3) << 3) | (((lane >> 4) & 1) << 2) | (lane & 3);
    auto writeV = [&](int bf) {
        #pragma unroll
        for (int e = 0; e < 8; ++e) {
            Vt[bf][(wave * 16 + e) * 72 + colp]     = vreg0[e];
            Vt[bf][(wave * 16 + 8 + e) * 72 + colp] = vreg1[e];
        }
    };

    stageK(0, 0);
    loadV(0);
    writeV(0);

    for (int t = 0; t < SEQ / 64; ++t) {
        __syncthreads();                         // tile t staged
        if (t + 1 < SEQ / 64) { stageK((t + 1) & 1, (t + 1) * 64); loadV((t + 1) * 64); }
        const int bf = t & 1;

        // S^T = K @ Q^T : lane holds S[q=lq][key = j*16 + lg*4 + r]  (RAW, unscaled)
        f32x4 sfr[4];
        __builtin_amdgcn_s_setprio(1);
        #pragma unroll
        for (int j = 0; j < 4; ++j) {
            const int key = j * 16 + lq;
            bf16x8 k0 = *(const bf16x8*)&Ks[bf][key * 64 + ((lg * 8) ^ ((lq & 7) * 8))];
            bf16x8 k1 = *(const bf16x8*)&Ks[bf][key * 64 + ((32 + lg * 8) ^ ((lq & 7) * 8))];
            f32x4 z = {0.f, 0.f, 0.f, 0.f};
            z = __builtin_amdgcn_mfma_f32_16x16x32_bf16(k0, aQ[0], z, 0, 0, 0);
            z = __builtin_amdgcn_mfma_f32_16x16x32_bf16(k1, aQ[1], z, 0, 0, 0);
            sfr[j] = z;
        }
        __builtin_amdgcn_s_setprio(0);

        // online softmax for q=lq (raw-score domain; scale folded into exp2)
        float mx = -1e30f;
        #pragma unroll
        for (int j = 0; j < 4; ++j)
            #pragma unroll
            for (int r = 0; r < 4; ++r) mx = fmaxf(mx, sfr[j][r]);
        mx = fmaxf(mx, __shfl_xor(mx, 16));
        mx = fmaxf(mx, __shfl_xor(mx, 32));
        // defer-max: only rescale when max grew by > 64 raw (= 8 scaled)
        if (!__all(mx - mrun <= 64.0f)) {
            const float mn = fmaxf(mrun, mx);
            const float corr = exp2f((mrun - mn) * CEXP);
            mrun = mn;
            lrun *= corr;
            float corr4[4];
            #pragma unroll
            for (int r = 0; r < 4; ++r) corr4[r] = __shfl(corr, lg * 4 + r, 16);
            #pragma unroll
            for (int j = 0; j < 4; ++j)
                #pragma unroll
                for (int r = 0; r < 4; ++r) oacc[j][r] *= corr4[r];
        }

        // P = exp2((S - m)*CEXP); keep in registers, truncate-pack to bf16 pairs
        uint32_t pu[4][2];
        float rsum = 0.f;
        #pragma unroll
        for (int j = 0; j < 4; ++j) {
            float p0 = exp2f((sfr[j][0] - mrun) * CEXP);
            float p1 = exp2f((sfr[j][1] - mrun) * CEXP);
            float p2 = exp2f((sfr[j][2] - mrun) * CEXP);
            float p3 = exp2f((sfr[j][3] - mrun) * CEXP);
            rsum += (p0 + p1) + (p2 + p3);
            pu[j][0] = (fbits(p0) >> 16) | (fbits(p1) & 0xFFFF0000u);
            pu[j][1] = (fbits(p2) >> 16) | (fbits(p3) & 0xFFFF0000u);
        }
        rsum += __shfl_xor(rsum, 16);
        rsum += __shfl_xor(rsum, 32);
        lrun += rsum;

        // O += P @ V  (A = own registers; B = Vt rows with matching key permutation)
        __builtin_amdgcn_s_setprio(1);
        #pragma unroll
        for (int kk = 0; kk < 2; ++kk) {
            union { u32x4 u; bf16x8 v; } ap;
            ap.u[0] = pu[2 * kk][0];     ap.u[1] = pu[2 * kk][1];
            ap.u[2] = pu[2 * kk + 1][0]; ap.u[3] = pu[2 * kk + 1][1];
            #pragma unroll
            for (int j = 0; j < 4; ++j) {
                bf16x8 bv = *(const bf16x8*)&Vt[bf][(j * 16 + lq) * 72 + kk * 32 + lg * 8];
                oacc[j] = __builtin_amdgcn_mfma_f32_16x16x32_bf16(ap.v, bv, oacc[j], 0, 0, 0);
            }
        }
        __builtin_amdgcn_s_setprio(0);

        if (t + 1 < SEQ / 64) writeV((t + 1) & 1);   // other buffer; sync'd at loop top
    }

    // epilogue: O[q = lg*4+r][d = j*16+lq] / l[q]
    float linv[4];
    #pragma unroll
    for (int r = 0; r < 4; ++r) linv[r] = 1.f / __shfl(lrun, lg * 4 + r, 16);
    #pragma unroll
    for (int j = 0; j < 4; ++j) {
        #pragma unroll
        for (int r = 0; r < 4; ++r) {
            const int qrow = qt * 64 + wave * 16 + lg * 4 + r;
            Og[(rowbase + qrow) * D_MODEL + colh + j * 16 + lq] = f2bf(oacc[j][r] * linv[r]);
        }
    }
}

// ---------------- launch ----------------
extern "C" void kernel_launch(void* const* d_in, const int* in_sizes, int n_in,
                              void* d_out, int out_size, void* d_ws, size_t ws_size,
                              hipStream_t stream) {
    const float* x    = (const float*)d_in[0];
    const float* ln1g = (const float*)d_in[1];
    const float* ln1b = (const float*)d_in[2];
    const float* wq   = (const float*)d_in[3];
    const float* bq   = (const float*)d_in[4];
    const float* wk   = (const float*)d_in[5];
    const float* bk   = (const float*)d_in[6];
    const float* wv   = (const float*)d_in[7];
    const float* bv   = (const float*)d_in[8];
    const float* wo   = (const float*)d_in[9];
    const float* bo   = (const float*)d_in[10];
    const float* ln2g = (const float*)d_in[11];
    const float* ln2b = (const float*)d_in[12];
    const float* w1   = (const float*)d_in[13];
    const float* b1   = (const float*)d_in[14];
    const float* w2   = (const float*)d_in[15];
    const float* b2   = (const float*)d_in[16];

    const size_t M1 = 1048576;
    unsigned short* wqkvb = (unsigned short*)d_ws;        // [3072][1024] bf16
    unsigned short* wob   = wqkvb + 3 * M1;
    unsigned short* w1b   = wqkvb + 4 * M1;
    unsigned short* w2b   = wqkvb + 6 * M1;
    float*          bias3 = (float*)(wqkvb + 8 * M1);     // 3072 f32
    unsigned short* x2    = (unsigned short*)(bias3 + 3072);
    unsigned short* qkv   = x2 + (size_t)ROWS * D_MODEL;  // [4096][3072] bf16
    float*          x1    = (float*)(qkv + (size_t)ROWS * 3072);
    unsigned short* attn_o = x2;                          // reuse
    unsigned short* x4    = qkv;                          // reuse
    unsigned short* hb    = qkv + (size_t)ROWS * D_MODEL; // reuse, [4096][2048]

    cvt_weights<<<8204, 256, 0, stream>>>(wq, wk, wv, wo, w1, w2, wqkvb,
                                          bq, bk, bv, bias3);
    ln_bf16<<<ROWS, 256, 0, stream>>>(x, ln1g, ln1b, x2);

    // fused QKV: [4096,1024] @ [3072,1024]^T
    gemm_bt<128, 128, 0><<<dim3(24, 32), 256, 0, stream>>>(
        x2, wqkvb, bias3, nullptr, qkv, nullptr, ROWS, 3072, 1024);

    attn_kernel<<<dim3(SEQ / 64, BATCH * HEADS), 256, 0, stream>>>(
        qkv, qkv + 1024, qkv + 2048, attn_o, 3072);

    gemm_bt<128, 64, 2><<<dim3(16, 32), 256, 0, stream>>>(
        attn_o, wob, bo, x, nullptr, x1, ROWS, 1024, 1024);

    ln_bf16<<<ROWS, 256, 0, stream>>>(x1, ln2g, ln2b, x4);

    gemm_bt<128, 128, 1><<<dim3(16, 32), 256, 0, stream>>>(
        x4, w1b, b1, nullptr, hb, nullptr, ROWS, D_FF, 1024);

    gemm_bt<128, 64, 2><<<dim3(16, 32), 256, 0, stream>>>(
        hb, w2b, b2, x1, nullptr, (float*)d_out, ROWS, 1024, D_FF);
}